// Round 5
// baseline (183.690 us; speedup 1.0000x reference)
//
#include <hip/hip_runtime.h>

// SSIM, fused separable, barrier-free column-sliding register design, v3.
// vs R4: (1) aligned dwordx4 loads (4/img from (gx-5)&~3, per-load clamped
// column offsets; Wp[14] masked weights absorb alignment shift + x-edges),
// (2) double-buffered register prefetch: next row's 8 loads issue before the
// current row's compute -> counted vmcnt, latency hidden under ~350cyc VALU,
// (3) RING=12 so buffer parity (mod 2) and ring phase (mod 12) share one
// compile-time index; STRIP_H=64 (warmup 10/74, 768 blocks = 3/CU exact).

#define IMG_H 512
#define IMG_W 512
#define N_PLANES 48
#define KW 11
#define RING 12
#define STRIP_W 256
#define STRIP_H 64
#define BLOCK 256
#define STRIPS_X (IMG_W / STRIP_W)             // 2
#define STRIPS_Y (IMG_H / STRIP_H)             // 8
#define NBLK (N_PLANES * STRIPS_X * STRIPS_Y)  // 768
#define C1_CONST 1.0e-4f
#define C2_CONST 9.0e-4f

__device__ __forceinline__ float bcastf(float x) {
  return __uint_as_float(__builtin_amdgcn_readfirstlane(__float_as_uint(x)));
}

// One H-pass tap at span element E (component C of float4 (E>>2)), buffer BUF.
#define TAPE(E, C, BUF) { \
    const float w_  = Wp[(E)]; \
    const float x1_ = bA[(BUF)][(E)>>2].C; \
    const float x2_ = bB[(BUF)][(E)>>2].C; \
    const float t1_ = w_ * x1_; const float t2_ = w_ * x2_; \
    m1_ += t1_; m2_ += t2_; \
    q12_ += t1_ * x2_; qs_ += t1_ * x1_; qs_ += t2_ * x2_; }

// One V-pass tap k reading ring slot QQ.
#define EMT(K, QQ) { const float w_ = wkr[(K)]; \
    vm1_ += w_ * rm1[(QQ)]; vm2_ += w_ * rm2[(QQ)]; \
    vqs_ += w_ * rqs[(QQ)]; vq12_ += w_ * rq12[(QQ)]; }

// Load row ROW (if valid) into buffer B. Aligned dwordx4, clamped offsets.
#define PRELOAD(B, ROW) { \
    const int rn_ = (ROW); \
    if (rn_ >= 0 && rn_ < IMG_H) { \
      const float* __restrict__ rp1_ = p1 + (size_t)rn_ * IMG_W; \
      const float* __restrict__ rp2_ = p2 + (size_t)rn_ * IMG_W; \
      bA[(B)][0] = *(const float4*)(rp1_ + off0); \
      bA[(B)][1] = *(const float4*)(rp1_ + off1); \
      bA[(B)][2] = *(const float4*)(rp1_ + off2); \
      bA[(B)][3] = *(const float4*)(rp1_ + off3); \
      bB[(B)][0] = *(const float4*)(rp2_ + off0); \
      bB[(B)][1] = *(const float4*)(rp2_ + off1); \
      bB[(B)][2] = *(const float4*)(rp2_ + off2); \
      bB[(B)][3] = *(const float4*)(rp2_ + off3); \
    } }

// One pipeline step. Q = step mod 12 (compile-time). Prefetch row gr+1 into
// buffer (Q+1)&1, compute H-pass of row gr from buffer Q&1 into ring slot Q,
// optionally emit output row gr-5 from ring slots (Q+2+k)%12.
#define STEP12(Q, EMIT) { \
  PRELOAD(((Q)+1)&1, gr + 1) \
  if (gr >= 0 && gr < IMG_H) { \
    float m1_ = 0.f, m2_ = 0.f, qs_ = 0.f, q12_ = 0.f; \
    TAPE(0,x,(Q)&1)  TAPE(1,y,(Q)&1)  TAPE(2,z,(Q)&1)  TAPE(3,w,(Q)&1) \
    TAPE(4,x,(Q)&1)  TAPE(5,y,(Q)&1)  TAPE(6,z,(Q)&1)  TAPE(7,w,(Q)&1) \
    TAPE(8,x,(Q)&1)  TAPE(9,y,(Q)&1)  TAPE(10,z,(Q)&1) TAPE(11,w,(Q)&1) \
    TAPE(12,x,(Q)&1) TAPE(13,y,(Q)&1) \
    rm1[(Q)] = m1_; rm2[(Q)] = m2_; rqs[(Q)] = qs_; rq12[(Q)] = q12_; \
  } else { \
    rm1[(Q)] = 0.f; rm2[(Q)] = 0.f; rqs[(Q)] = 0.f; rq12[(Q)] = 0.f; } \
  if (EMIT) { \
    float vm1_ = 0.f, vm2_ = 0.f, vqs_ = 0.f, vq12_ = 0.f; \
    EMT(0, ((Q)+2)%RING)  EMT(1, ((Q)+3)%RING)  EMT(2, ((Q)+4)%RING) \
    EMT(3, ((Q)+5)%RING)  EMT(4, ((Q)+6)%RING)  EMT(5, ((Q)+7)%RING) \
    EMT(6, ((Q)+8)%RING)  EMT(7, ((Q)+9)%RING)  EMT(8, ((Q)+10)%RING) \
    EMT(9, ((Q)+11)%RING) EMT(10, (Q)) \
    const float mu11_ = vm1_ * vm1_; \
    const float mu22_ = vm2_ * vm2_; \
    const float mu12_ = vm1_ * vm2_; \
    const float musum_ = mu11_ + mu22_; \
    const float sigs_  = vqs_  - musum_; \
    const float sig12_ = vq12_ - mu12_; \
    const float num_ = (2.f * mu12_ + C1_CONST) * (2.f * sig12_ + C2_CONST); \
    const float den_ = (musum_ + C1_CONST) * (sigs_ + C2_CONST); \
    acc += num_ * __builtin_amdgcn_rcpf(den_); \
  } \
  gr++; \
}

__global__ __launch_bounds__(BLOCK) void ssim_strip_kernel(
    const float* __restrict__ img1,
    const float* __restrict__ img2,
    const float* __restrict__ kern2d,
    float* __restrict__ partial)
{
  __shared__ float wk_lds[KW];
  __shared__ float wave_sums[BLOCK / 64];

  const int tid = threadIdx.x;

  // 1D kernel = row sums of the normalized 2D kernel (== normalized 1D Gaussian).
  if (tid < KW) {
    float s = 0.f;
    #pragma unroll
    for (int j = 0; j < KW; ++j) s += kern2d[tid * KW + j];
    wk_lds[tid] = s;
  }
  __syncthreads();

  // V-pass weights, wave-uniform (SGPRs).
  float wkr[KW];
  #pragma unroll
  for (int k = 0; k < KW; ++k) wkr[k] = bcastf(wk_lds[k]);

  const int bid   = blockIdx.x;
  const int plane = bid / (STRIPS_X * STRIPS_Y);
  const int srem  = bid % (STRIPS_X * STRIPS_Y);
  const int y0    = (srem / STRIPS_X) * STRIP_H;
  const int x0    = (srem % STRIPS_X) * STRIP_W;
  const float* __restrict__ p1 = img1 + (size_t)plane * IMG_H * IMG_W;
  const float* __restrict__ p2 = img2 + (size_t)plane * IMG_H * IMG_W;

  const int gx    = x0 + tid;          // this thread's output column
  const int bc    = gx - 5;            // window start (may be <0)
  const int base4 = bc & ~3;           // aligned span start (may be <0)
  const int r     = bc - base4;        // 0..3 alignment shift

  // Clamped, row-invariant load offsets (whole-float4 OOB granularity:
  // base4 % 4 == 0 and IMG_W % 4 == 0, so clamped loads are exactly the
  // ones whose intended columns are entirely OOB; Wp zeroes their taps).
  const int off0 = min(max(base4,      0), IMG_W - 4);
  const int off1 = min(max(base4 + 4,  0), IMG_W - 4);
  const int off2 = min(max(base4 + 8,  0), IMG_W - 4);
  const int off3 = min(max(base4 + 12, 0), IMG_W - 4);

  // Per-lane masked H-pass weights over the 16-float span (taps live at
  // e = r..r+10; zero outside window or outside image bounds).
  float Wp[14];
  #pragma unroll
  for (int e = 0; e < 14; ++e) {
    const int k   = e - r;
    const int col = base4 + e;
    Wp[e] = (k >= 0 && k <= 10 && col >= 0 && col < IMG_W) ? wk_lds[k] : 0.f;
  }

  float4 bA[2][4], bB[2][4];
  #pragma unroll
  for (int b = 0; b < 2; ++b)
    #pragma unroll
    for (int l = 0; l < 4; ++l) { bA[b][l] = float4{0,0,0,0}; bB[b][l] = float4{0,0,0,0}; }

  float rm1[RING], rm2[RING], rqs[RING], rq12[RING];
  float acc = 0.f;
  int gr = y0 - 5;

  PRELOAD(0, gr)   // row y0-5 into buffer 0

  // 74 steps: 10 warmup, 64 emitting. Step phase Q = step % 12 (compile-time);
  // buffer parity Q&1, ring slot Q.
  STEP12(0, 0) STEP12(1, 0) STEP12(2, 0) STEP12(3, 0) STEP12(4, 0)
  STEP12(5, 0) STEP12(6, 0) STEP12(7, 0) STEP12(8, 0) STEP12(9, 0)
  STEP12(10, 1) STEP12(11, 1)
  #pragma unroll 1
  for (int it = 0; it < 5; ++it) {
    STEP12(0, 1) STEP12(1, 1) STEP12(2, 1) STEP12(3, 1) STEP12(4, 1)
    STEP12(5, 1) STEP12(6, 1) STEP12(7, 1) STEP12(8, 1) STEP12(9, 1)
    STEP12(10, 1) STEP12(11, 1)
  }
  STEP12(0, 1) STEP12(1, 1)

  // Block reduction.
  #pragma unroll
  for (int off = 32; off > 0; off >>= 1)
    acc += __shfl_down(acc, off, 64);
  if ((tid & 63) == 0) wave_sums[tid >> 6] = acc;
  __syncthreads();
  if (tid == 0)
    partial[bid] = wave_sums[0] + wave_sums[1] + wave_sums[2] + wave_sums[3];
}

__global__ __launch_bounds__(256) void ssim_reduce_kernel(
    const float* __restrict__ partial, float* __restrict__ out)
{
  const int tid = threadIdx.x;
  double acc = 0.0;
  for (int i = tid; i < NBLK; i += 256) acc += (double)partial[i];
  #pragma unroll
  for (int off = 32; off > 0; off >>= 1)
    acc += __shfl_down(acc, off, 64);
  __shared__ double wsums[4];
  if ((tid & 63) == 0) wsums[tid >> 6] = acc;
  __syncthreads();
  if (tid == 0) {
    const double total = wsums[0] + wsums[1] + wsums[2] + wsums[3];
    const double inv_n = 1.0 / ((double)N_PLANES * IMG_H * IMG_W);
    out[0] = (float)(total * inv_n);
  }
}

extern "C" void kernel_launch(void* const* d_in, const int* in_sizes, int n_in,
                              void* d_out, int out_size, void* d_ws, size_t ws_size,
                              hipStream_t stream)
{
  const float* img1 = (const float*)d_in[0];
  const float* img2 = (const float*)d_in[1];
  const float* kern = (const float*)d_in[2];
  float* out = (float*)d_out;
  float* partial = (float*)d_ws;   // NBLK floats = 3 KiB

  ssim_strip_kernel<<<NBLK, BLOCK, 0, stream>>>(img1, img2, kern, partial);
  ssim_reduce_kernel<<<1, 256, 0, stream>>>(partial, out);
}

// Round 6
// 132.792 us; speedup vs baseline: 1.3833x; 1.3833x over previous
//
#include <hip/hip_runtime.h>

// SSIM, fused separable, column-sliding register ring + wave-private LDS row
// staging. v4.
// R4's bound was L1 line throughput: per-lane overlapping unaligned 16B global
// loads touched ~102 cache lines per wave-row (minimum ~10). Here each wave
// loads its 80-float row span once (1 dwordx4 instr per image, 20 active
// lanes = 5 lines), stages it in a wave-private LDS slice (no barriers; DS ops
// within a wave are in-order), and lanes re-read their 16-float aligned
// windows via ds_read_b128. Per-lane masked weights Wp[14] absorb the
// alignment shift and x-edges (R5-verified mechanism). T14 split: next row's
// global loads issue before current row's compute; ds_write after.
// V-pass = 4-quantity x 11-deep register ring, pure FMAs.

#define IMG_H 512
#define IMG_W 512
#define N_PLANES 48
#define KW 11
#define RING 11
#define BLOCK 256
#define WAVE_COLS 64
#define STRIP_H 64
#define COLG_PER_BLOCK 4                       // 4 waves x 64 cols = 256 cols
#define BLOCKS_X (IMG_W / (WAVE_COLS * COLG_PER_BLOCK))   // 2
#define BLOCKS_Y (IMG_H / STRIP_H)                        // 8
#define NBLK (N_PLANES * BLOCKS_X * BLOCKS_Y)             // 768
#define C1_CONST 1.0e-4f
#define C2_CONST 9.0e-4f

__device__ __forceinline__ float bcastf(float x) {
  return __uint_as_float(__builtin_amdgcn_readfirstlane(__float_as_uint(x)));
}

// One H-pass tap at window element E (taps live at e in [r, r+10]).
#define TAPX(E, AV, BV) { const float w_ = Wp[(E)]; \
    const float t1_ = w_ * (AV); const float t2_ = w_ * (BV); \
    m1_ += t1_; m2_ += t2_; \
    q12_ += t1_ * (BV); qs_ += t1_ * (AV); qs_ += t2_ * (BV); }

// One V-pass tap K reading ring slot QQ.
#define EMT(K, QQ) { const float w_ = wkr[(K)]; \
    vm1_ += w_ * rm1[(QQ)]; vm2_ += w_ * rm2[(QQ)]; \
    vqs_ += w_ * rqs[(QQ)]; vq12_ += w_ * rq12[(QQ)]; }

// One pipeline step, phase Q = step % 11 (compile-time).
// 1) issue global loads for row gr+1 (20 lanes, dwordx4)      [latency hidden
// 2) ds_read row gr window, H-pass -> ring slot Q              under step's
// 3) emit output row gr-5 from ring (if EMIT)                  compute]
// 4) ds_write row gr+1 into the wave-private slice (after reads; in-order)
#define STEPQ(Q, EMIT) { \
  const int nr_ = gr + 1; \
  const bool nrv_ = (nr_ >= 0) & (nr_ < IMG_H); \
  float4 g1_, g2_; \
  if (act20 & nrv_) { \
    const size_t ro_ = (size_t)nr_ * IMG_W + c0; \
    g1_ = *(const float4*)(p1 + ro_); \
    g2_ = *(const float4*)(p2 + ro_); \
  } \
  if (gr >= 0 && gr < IMG_H) { \
    const float4 A0 = *(const float4*)(sl1 + a); \
    const float4 A1 = *(const float4*)(sl1 + a + 4); \
    const float4 A2 = *(const float4*)(sl1 + a + 8); \
    const float4 A3 = *(const float4*)(sl1 + a + 12); \
    const float4 B0 = *(const float4*)(sl2 + a); \
    const float4 B1 = *(const float4*)(sl2 + a + 4); \
    const float4 B2 = *(const float4*)(sl2 + a + 8); \
    const float4 B3 = *(const float4*)(sl2 + a + 12); \
    float m1_ = 0.f, m2_ = 0.f, qs_ = 0.f, q12_ = 0.f; \
    TAPX(0,  A0.x, B0.x) TAPX(1,  A0.y, B0.y) TAPX(2,  A0.z, B0.z) \
    TAPX(3,  A0.w, B0.w) TAPX(4,  A1.x, B1.x) TAPX(5,  A1.y, B1.y) \
    TAPX(6,  A1.z, B1.z) TAPX(7,  A1.w, B1.w) TAPX(8,  A2.x, B2.x) \
    TAPX(9,  A2.y, B2.y) TAPX(10, A2.z, B2.z) TAPX(11, A2.w, B2.w) \
    TAPX(12, A3.x, B3.x) TAPX(13, A3.y, B3.y) \
    rm1[(Q)] = m1_; rm2[(Q)] = m2_; rqs[(Q)] = qs_; rq12[(Q)] = q12_; \
  } else { \
    rm1[(Q)] = 0.f; rm2[(Q)] = 0.f; rqs[(Q)] = 0.f; rq12[(Q)] = 0.f; } \
  if (EMIT) { \
    float vm1_ = 0.f, vm2_ = 0.f, vqs_ = 0.f, vq12_ = 0.f; \
    EMT(0, ((Q)+1)%RING)  EMT(1, ((Q)+2)%RING)  EMT(2, ((Q)+3)%RING) \
    EMT(3, ((Q)+4)%RING)  EMT(4, ((Q)+5)%RING)  EMT(5, ((Q)+6)%RING) \
    EMT(6, ((Q)+7)%RING)  EMT(7, ((Q)+8)%RING)  EMT(8, ((Q)+9)%RING) \
    EMT(9, ((Q)+10)%RING) EMT(10, (Q)) \
    const float mu11_ = vm1_ * vm1_; \
    const float mu22_ = vm2_ * vm2_; \
    const float mu12_ = vm1_ * vm2_; \
    const float musum_ = mu11_ + mu22_; \
    const float sigs_  = vqs_  - musum_; \
    const float sig12_ = vq12_ - mu12_; \
    const float num_ = (2.f * mu12_ + C1_CONST) * (2.f * sig12_ + C2_CONST); \
    const float den_ = (musum_ + C1_CONST) * (sigs_ + C2_CONST); \
    acc += num_ * __builtin_amdgcn_rcpf(den_); \
  } \
  if (act20 & nrv_) { \
    *(float4*)(sl1 + 4 * lane) = g1_; \
    *(float4*)(sl2 + 4 * lane) = g2_; \
  } \
  gr++; \
}

__global__ __launch_bounds__(BLOCK) void ssim_strip_kernel(
    const float* __restrict__ img1,
    const float* __restrict__ img2,
    const float* __restrict__ kern2d,
    float* __restrict__ partial)
{
  // Wave-private row slices: [wave][img][80 floats]. 2560 B total.
  __shared__ float slice[COLG_PER_BLOCK][2][80];
  __shared__ float wk_lds[KW];
  __shared__ float wave_sums[BLOCK / 64];

  const int tid  = threadIdx.x;
  const int wid  = tid >> 6;
  const int lane = tid & 63;

  // 1D kernel = row sums of the normalized 2D kernel (== normalized 1D Gaussian).
  if (tid < KW) {
    float s = 0.f;
    #pragma unroll
    for (int j = 0; j < KW; ++j) s += kern2d[tid * KW + j];
    wk_lds[tid] = s;
  }
  __syncthreads();

  // V-pass weights, wave-uniform (SGPRs).
  float wkr[KW];
  #pragma unroll
  for (int k = 0; k < KW; ++k) wkr[k] = bcastf(wk_lds[k]);

  const int bid   = blockIdx.x;
  const int plane = bid / (BLOCKS_X * BLOCKS_Y);
  const int srem  = bid % (BLOCKS_X * BLOCKS_Y);
  const int y0    = (srem / BLOCKS_X) * STRIP_H;
  const int x0b   = (srem % BLOCKS_X) * (WAVE_COLS * COLG_PER_BLOCK);
  const float* __restrict__ p1 = img1 + (size_t)plane * IMG_H * IMG_W;
  const float* __restrict__ p2 = img2 + (size_t)plane * IMG_H * IMG_W;

  const int x0w   = x0b + wid * WAVE_COLS;   // wave's first column
  const int gx    = x0w + lane;              // this thread's output column
  const int wbase = x0w - 8;                 // slice float 0 <-> global col wbase

  // Window: lane reads slice floats [a, a+15]; taps at e in [r, r+10], tap k
  // weight wk[e-r]; zero where the global column wbase+a+e is out of image.
  const int a = (lane + 3) & ~3;
  const int r = (lane + 3) & 3;

  float Wp[14];
  #pragma unroll
  for (int e = 0; e < 14; ++e) {
    const int k   = e - r;
    const int col = wbase + a + e;
    Wp[e] = (k >= 0 && k <= 10 && col >= 0 && col < IMG_W) ? wk_lds[k] : 0.f;
  }

  // Cooperative row staging: lanes 0..19 each load one dwordx4 (16 B) per
  // image covering slice floats 4*lane..4*lane+3. wbase % 4 == 0 and
  // IMG_W % 4 == 0, so each 4-float group is entirely in- or out-of-image;
  // clamped addresses only affect fully-OOB groups (Wp zeroes those taps).
  const bool act20 = (lane < 20);
  int c0r = wbase + 4 * lane;
  const int c0 = c0r < 0 ? 0 : (c0r > IMG_W - 4 ? IMG_W - 4 : c0r);

  float* sl1 = &slice[wid][0][0];
  float* sl2 = &slice[wid][1][0];

  float rm1[RING], rm2[RING], rqs[RING], rq12[RING];
  float acc = 0.f;
  int gr = y0 - 5;

  // Prologue: stage row y0-5 (if valid).
  if (act20 && gr >= 0) {
    const size_t ro = (size_t)gr * IMG_W + c0;
    *(float4*)(sl1 + 4 * lane) = *(const float4*)(p1 + ro);
    *(float4*)(sl2 + 4 * lane) = *(const float4*)(p2 + ro);
  }

  // 74 steps: 10 warmup, 64 emitting. Phase Q = step % 11 (compile-time).
  STEPQ(0, 0) STEPQ(1, 0) STEPQ(2, 0) STEPQ(3, 0) STEPQ(4, 0)
  STEPQ(5, 0) STEPQ(6, 0) STEPQ(7, 0) STEPQ(8, 0) STEPQ(9, 0)
  STEPQ(10, 1)
  #pragma unroll 1
  for (int it = 0; it < 5; ++it) {
    STEPQ(0, 1) STEPQ(1, 1) STEPQ(2, 1) STEPQ(3, 1) STEPQ(4, 1) STEPQ(5, 1)
    STEPQ(6, 1) STEPQ(7, 1) STEPQ(8, 1) STEPQ(9, 1) STEPQ(10, 1)
  }
  STEPQ(0, 1) STEPQ(1, 1) STEPQ(2, 1) STEPQ(3, 1)
  STEPQ(4, 1) STEPQ(5, 1) STEPQ(6, 1) STEPQ(7, 1)

  // Block reduction.
  #pragma unroll
  for (int off = 32; off > 0; off >>= 1)
    acc += __shfl_down(acc, off, 64);
  if ((tid & 63) == 0) wave_sums[tid >> 6] = acc;
  __syncthreads();
  if (tid == 0)
    partial[bid] = wave_sums[0] + wave_sums[1] + wave_sums[2] + wave_sums[3];
}

__global__ __launch_bounds__(256) void ssim_reduce_kernel(
    const float* __restrict__ partial, float* __restrict__ out)
{
  const int tid = threadIdx.x;
  double acc = 0.0;
  for (int i = tid; i < NBLK; i += 256) acc += (double)partial[i];
  #pragma unroll
  for (int off = 32; off > 0; off >>= 1)
    acc += __shfl_down(acc, off, 64);
  __shared__ double wsums[4];
  if ((tid & 63) == 0) wsums[tid >> 6] = acc;
  __syncthreads();
  if (tid == 0) {
    const double total = wsums[0] + wsums[1] + wsums[2] + wsums[3];
    const double inv_n = 1.0 / ((double)N_PLANES * IMG_H * IMG_W);
    out[0] = (float)(total * inv_n);
  }
}

extern "C" void kernel_launch(void* const* d_in, const int* in_sizes, int n_in,
                              void* d_out, int out_size, void* d_ws, size_t ws_size,
                              hipStream_t stream)
{
  const float* img1 = (const float*)d_in[0];
  const float* img2 = (const float*)d_in[1];
  const float* kern = (const float*)d_in[2];
  float* out = (float*)d_out;
  float* partial = (float*)d_ws;   // NBLK floats = 3 KiB

  ssim_strip_kernel<<<NBLK, BLOCK, 0, stream>>>(img1, img2, kern, partial);
  ssim_reduce_kernel<<<1, 256, 0, stream>>>(partial, out);
}

// Round 7
// 109.778 us; speedup vs baseline: 1.6733x; 1.2096x over previous
//
#include <hip/hip_runtime.h>

// SSIM, fused separable, column-sliding register ring + wave-private LDS row
// staging via global_load_lds DMA. v5.
// - Each wave owns 64 columns, slides down 74 rows; V-pass = 4-quantity x
//   12-slot register ring (pure FMA), no barriers in the main loop.
// - Row staging: 2x global_load_lds width=16 (20 active lanes) per row ->
//   wave-private double-buffered LDS slice. No staging VGPRs, no ds_write.
// - Latency hiding: issue next row's 2 DMAs first, then s_waitcnt vmcnt(2)
//   waits only for the PREVIOUS step's DMAs (in flight ~1 full step).
// - H-pass reads the 16-float aligned window back as ds_read (2 halves,
//   max 16 live window regs); per-lane masked weights Wp[14] absorb the
//   alignment shift and x-edges (R5/R6-verified mechanism).

#define IMG_H 512
#define IMG_W 512
#define N_PLANES 48
#define KW 11
#define RING 12
#define BLOCK 256
#define WAVE_COLS 64
#define STRIP_H 64
#define BLOCKS_X (IMG_W / (WAVE_COLS * 4))            // 2
#define BLOCKS_Y (IMG_H / STRIP_H)                    // 8
#define NBLK (N_PLANES * BLOCKS_X * BLOCKS_Y)         // 768
#define SLOT 160                                      // floats per buf per img
#define C1_CONST 1.0e-4f
#define C2_CONST 9.0e-4f

typedef const __attribute__((address_space(1))) void GV;
typedef __attribute__((address_space(3))) void LV;

__device__ __forceinline__ void dma16(const float* g, float* l) {
  __builtin_amdgcn_global_load_lds((GV*)g, (LV*)l, 16, 0, 0);
}

__device__ __forceinline__ float bcastf(float x) {
  return __uint_as_float(__builtin_amdgcn_readfirstlane(__float_as_uint(x)));
}

#define TAPX(E, AV, BV) { const float w_ = Wp[(E)]; \
    const float t1_ = w_ * (AV); const float t2_ = w_ * (BV); \
    m1_ += t1_; m2_ += t2_; \
    q12_ += t1_ * (BV); qs_ += t1_ * (AV); qs_ += t2_ * (BV); }

#define EMT(K, QQ) { const float w_ = wkr[(K)]; \
    vm1_ += w_ * rm1[(QQ)]; vm2_ += w_ * rm2[(QQ)]; \
    vqs_ += w_ * rqs[(QQ)]; vq12_ += w_ * rq12[(QQ)]; }

// One pipeline step, Q = step % 12 (compile-time). Buffer parity Q&1.
// 1) issue 2 DMAs for row gr+1 into buf (Q+1)&1   (stay in flight)
// 2) s_waitcnt vmcnt(2): previous step's DMAs (buf Q&1) now complete
// 3) ds_read window from buf Q&1, H-pass -> ring slot Q
// 4) emit output row gr-5 from ring (if EMIT)
#define STEPQ(Q, EMIT) { \
  { const int nr_ = gr + 1; \
    const int nrc_ = nr_ < 0 ? 0 : (nr_ > IMG_H - 1 ? IMG_H - 1 : nr_); \
    if (lane < 20) { \
      const size_t ro_ = (size_t)nrc_ * IMG_W + c0; \
      dma16(p1 + ro_, sl1 + (((Q) + 1) & 1) * SLOT); \
      dma16(p2 + ro_, sl2 + (((Q) + 1) & 1) * SLOT); \
    } } \
  asm volatile("s_waitcnt vmcnt(2)" ::: "memory"); \
  __builtin_amdgcn_sched_barrier(0); \
  if (gr >= 0 && gr < IMG_H) { \
    const float* sb1_ = sl1 + ((Q) & 1) * SLOT; \
    const float* sb2_ = sl2 + ((Q) & 1) * SLOT; \
    float m1_ = 0.f, m2_ = 0.f, qs_ = 0.f, q12_ = 0.f; \
    { const float4 A0 = *(const float4*)(sb1_ + a); \
      const float4 A1 = *(const float4*)(sb1_ + a + 4); \
      const float4 B0 = *(const float4*)(sb2_ + a); \
      const float4 B1 = *(const float4*)(sb2_ + a + 4); \
      TAPX(0, A0.x, B0.x) TAPX(1, A0.y, B0.y) TAPX(2, A0.z, B0.z) \
      TAPX(3, A0.w, B0.w) TAPX(4, A1.x, B1.x) TAPX(5, A1.y, B1.y) \
      TAPX(6, A1.z, B1.z) TAPX(7, A1.w, B1.w) } \
    { const float4 A2 = *(const float4*)(sb1_ + a + 8); \
      const float2 A3 = *(const float2*)(sb1_ + a + 12); \
      const float4 B2 = *(const float4*)(sb2_ + a + 8); \
      const float2 B3 = *(const float2*)(sb2_ + a + 12); \
      TAPX(8, A2.x, B2.x)  TAPX(9, A2.y, B2.y)  TAPX(10, A2.z, B2.z) \
      TAPX(11, A2.w, B2.w) TAPX(12, A3.x, B3.x) TAPX(13, A3.y, B3.y) } \
    rm1[(Q)] = m1_; rm2[(Q)] = m2_; rqs[(Q)] = qs_; rq12[(Q)] = q12_; \
  } else { \
    rm1[(Q)] = 0.f; rm2[(Q)] = 0.f; rqs[(Q)] = 0.f; rq12[(Q)] = 0.f; } \
  if (EMIT) { \
    float vm1_ = 0.f, vm2_ = 0.f, vqs_ = 0.f, vq12_ = 0.f; \
    EMT(0, ((Q)+2)%RING)  EMT(1, ((Q)+3)%RING)  EMT(2, ((Q)+4)%RING) \
    EMT(3, ((Q)+5)%RING)  EMT(4, ((Q)+6)%RING)  EMT(5, ((Q)+7)%RING) \
    EMT(6, ((Q)+8)%RING)  EMT(7, ((Q)+9)%RING)  EMT(8, ((Q)+10)%RING) \
    EMT(9, ((Q)+11)%RING) EMT(10, (Q)) \
    const float mu11_ = vm1_ * vm1_; \
    const float mu22_ = vm2_ * vm2_; \
    const float mu12_ = vm1_ * vm2_; \
    const float musum_ = mu11_ + mu22_; \
    const float sigs_  = vqs_  - musum_; \
    const float sig12_ = vq12_ - mu12_; \
    const float num_ = (2.f * mu12_ + C1_CONST) * (2.f * sig12_ + C2_CONST); \
    const float den_ = (musum_ + C1_CONST) * (sigs_ + C2_CONST); \
    acc += num_ * __builtin_amdgcn_rcpf(den_); \
  } \
  gr++; \
}

__global__ __launch_bounds__(BLOCK) void ssim_strip_kernel(
    const float* __restrict__ img1,
    const float* __restrict__ img2,
    const float* __restrict__ kern2d,
    float* __restrict__ partial)
{
  // Wave-private double-buffered row slices: [wave][buf][img][80]. 10 KiB.
  __shared__ __align__(16) float slice[4][2][2][80];
  __shared__ float wk_lds[KW];
  __shared__ float wave_sums[BLOCK / 64];

  const int tid  = threadIdx.x;
  const int wid  = tid >> 6;
  const int lane = tid & 63;

  // 1D kernel = row sums of the normalized 2D kernel (== normalized 1D Gaussian).
  if (tid < KW) {
    float s = 0.f;
    #pragma unroll
    for (int j = 0; j < KW; ++j) s += kern2d[tid * KW + j];
    wk_lds[tid] = s;
  }
  __syncthreads();

  // V-pass weights, wave-uniform (SGPRs).
  float wkr[KW];
  #pragma unroll
  for (int k = 0; k < KW; ++k) wkr[k] = bcastf(wk_lds[k]);

  const int bid   = blockIdx.x;
  const int plane = bid / (BLOCKS_X * BLOCKS_Y);
  const int srem  = bid % (BLOCKS_X * BLOCKS_Y);
  const int y0    = (srem / BLOCKS_X) * STRIP_H;
  const int x0b   = (srem % BLOCKS_X) * (WAVE_COLS * 4);
  const float* __restrict__ p1 = img1 + (size_t)plane * IMG_H * IMG_W;
  const float* __restrict__ p2 = img2 + (size_t)plane * IMG_H * IMG_W;

  const int x0w   = x0b + wid * WAVE_COLS;   // wave's first column
  const int gx    = x0w + lane;              // this thread's output column
  const int wbase = x0w - 8;                 // slice float 0 <-> global col wbase

  // Lane's window: slice floats [a, a+15]; taps at e in [r, r+10].
  const int a = (lane + 3) & ~3;
  const int r = (lane + 3) & 3;

  float Wp[14];
  #pragma unroll
  for (int e = 0; e < 14; ++e) {
    const int k   = e - r;
    const int col = wbase + a + e;
    Wp[e] = (k >= 0 && k <= 10 && col >= 0 && col < IMG_W) ? wk_lds[k] : 0.f;
  }

  // DMA source column for lanes 0..19 (16B chunk -> slice floats 4l..4l+3).
  // wbase % 4 == 0, IMG_W % 4 == 0: each 4-float group is entirely in- or
  // out-of-image; clamped addresses only affect fully-OOB groups (Wp-zeroed).
  const int c0r = wbase + 4 * lane;
  const int c0  = c0r < 0 ? 0 : (c0r > IMG_W - 4 ? IMG_W - 4 : c0r);

  float* sl1 = &slice[wid][0][0][0];   // img1; buf b at +b*SLOT
  float* sl2 = &slice[wid][0][1][0];   // img2; buf b at +b*SLOT

  float rm1[RING], rm2[RING], rqs[RING], rq12[RING];
  float acc = 0.f;
  int gr = y0 - 5;

  // Prologue: DMA row y0-5 (clamped; contents unused if invalid) into buf 0.
  {
    const int r0 = gr < 0 ? 0 : gr;
    if (lane < 20) {
      const size_t ro = (size_t)r0 * IMG_W + c0;
      dma16(p1 + ro, sl1);
      dma16(p2 + ro, sl2);
    }
  }

  // 74 steps: 10 warmup, 64 emitting. Q = step % 12 (compile-time).
  STEPQ(0, 0) STEPQ(1, 0) STEPQ(2, 0) STEPQ(3, 0) STEPQ(4, 0)
  STEPQ(5, 0) STEPQ(6, 0) STEPQ(7, 0) STEPQ(8, 0) STEPQ(9, 0)
  STEPQ(10, 1) STEPQ(11, 1)
  #pragma unroll 1
  for (int it = 0; it < 5; ++it) {
    STEPQ(0, 1) STEPQ(1, 1) STEPQ(2, 1) STEPQ(3, 1) STEPQ(4, 1)
    STEPQ(5, 1) STEPQ(6, 1) STEPQ(7, 1) STEPQ(8, 1) STEPQ(9, 1)
    STEPQ(10, 1) STEPQ(11, 1)
  }
  STEPQ(0, 1) STEPQ(1, 1)

  // Block reduction.
  #pragma unroll
  for (int off = 32; off > 0; off >>= 1)
    acc += __shfl_down(acc, off, 64);
  if ((tid & 63) == 0) wave_sums[tid >> 6] = acc;
  __syncthreads();
  if (tid == 0)
    partial[bid] = wave_sums[0] + wave_sums[1] + wave_sums[2] + wave_sums[3];
}

__global__ __launch_bounds__(256) void ssim_reduce_kernel(
    const float* __restrict__ partial, float* __restrict__ out)
{
  const int tid = threadIdx.x;
  double acc = 0.0;
  for (int i = tid; i < NBLK; i += 256) acc += (double)partial[i];
  #pragma unroll
  for (int off = 32; off > 0; off >>= 1)
    acc += __shfl_down(acc, off, 64);
  __shared__ double wsums[4];
  if ((tid & 63) == 0) wsums[tid >> 6] = acc;
  __syncthreads();
  if (tid == 0) {
    const double total = wsums[0] + wsums[1] + wsums[2] + wsums[3];
    const double inv_n = 1.0 / ((double)N_PLANES * IMG_H * IMG_W);
    out[0] = (float)(total * inv_n);
  }
}

extern "C" void kernel_launch(void* const* d_in, const int* in_sizes, int n_in,
                              void* d_out, int out_size, void* d_ws, size_t ws_size,
                              hipStream_t stream)
{
  const float* img1 = (const float*)d_in[0];
  const float* img2 = (const float*)d_in[1];
  const float* kern = (const float*)d_in[2];
  float* out = (float*)d_out;
  float* partial = (float*)d_ws;   // NBLK floats = 3 KiB

  ssim_strip_kernel<<<NBLK, BLOCK, 0, stream>>>(img1, img2, kern, partial);
  ssim_reduce_kernel<<<1, 256, 0, stream>>>(partial, out);
}